// Round 1
// baseline (5405.460 us; speedup 1.0000x reference)
//
#include <hip/hip_runtime.h>

// RandomWalkPositionalEncoding: out[i, k-1] = diag(P^k)[i], k=1..10, P = A/(deg+1e-8)
// Using S = D^-1/2 A D^-1/2 (symmetric): diag(P^k) = diag(S^k);
//   diag(S^{2m}) = rowwise ||W_m||^2, diag(S^{2m+1}) = <W_m, W_{m+1}> where W_m = S^m E_block.

#define NN 8192
#define NWORDS 256            // NN/32 u32 words per bitmap row
#define EMB 32

typedef float f4 __attribute__((ext_vector_type(4)));

__global__ void scatter_edges(const int* __restrict__ ei, unsigned* __restrict__ bm, int nE) {
    int e = blockIdx.x * blockDim.x + threadIdx.x;
    if (e >= nE) return;
    int r = ei[e];
    int c = ei[nE + e];
    atomicOr(&bm[(size_t)r * NWORDS + (c >> 5)], 1u << (c & 31));
    atomicOr(&bm[(size_t)c * NWORDS + (r >> 5)], 1u << (r & 31));
}

// one wave per row: popcount 256 words, write degree, dinv_sqrt, and k=1 diagonal.
__global__ void degree_kernel(const unsigned* __restrict__ bm, int* __restrict__ deg,
                              float* __restrict__ dinv, float* __restrict__ out) {
    int lane = threadIdx.x & 63;
    int r = blockIdx.x * (blockDim.x >> 6) + (threadIdx.x >> 6);
    const unsigned* row = bm + (size_t)r * NWORDS;
    uint4 w = *(const uint4*)(row + lane * 4);
    int cnt = __popc(w.x) + __popc(w.y) + __popc(w.z) + __popc(w.w);
    for (int d = 32; d; d >>= 1) cnt += __shfl_down(cnt, d);
    if (lane == 0) {
        deg[r] = cnt;
        float dt = (float)cnt + 1e-8f;       // matches reference f32 rounding
        dinv[r] = rsqrtf(dt);
        unsigned selfw = row[r >> 5];
        out[(size_t)r * EMB] = ((selfw >> (r & 31)) & 1u) ? (1.0f / dt) : 0.0f;
    }
}

// single-block exclusive scan of 8192 degrees -> rowptr[0..8192]
__global__ void scan_kernel(const int* __restrict__ deg, int* __restrict__ rowptr) {
    __shared__ int wsum[4];
    __shared__ int base;
    int tid = threadIdx.x;          // 256 threads
    int lane = tid & 63, wid = tid >> 6;
    if (tid == 0) base = 0;
    __syncthreads();
    for (int ch = 0; ch < NN / 256; ++ch) {
        int idx = ch * 256 + tid;
        int v = deg[idx];
        int s = v;
#pragma unroll
        for (int d = 1; d < 64; d <<= 1) {
            int t = __shfl_up(s, d);
            if (lane >= d) s += t;
        }
        if (lane == 63) wsum[wid] = s;
        __syncthreads();
        int ofs = base;
        for (int w = 0; w < wid; ++w) ofs += wsum[w];
        rowptr[idx] = ofs + s - v;
        int tot = wsum[0] + wsum[1] + wsum[2] + wsum[3];
        __syncthreads();
        if (tid == 0) base += tot;
        __syncthreads();
    }
    if (tid == 0) rowptr[NN] = base;
}

// thread per row: expand bitmap row -> CSR cols + values S[r,c] = dinv[r]*dinv[c]
__global__ void fill_csr(const unsigned* __restrict__ bm, const int* __restrict__ rowptr,
                         const float* __restrict__ dinv, int* __restrict__ ccol,
                         float* __restrict__ cval) {
    int r = blockIdx.x * blockDim.x + threadIdx.x;
    if (r >= NN) return;
    int p = rowptr[r];
    float dr = dinv[r];
    const unsigned* row = bm + (size_t)r * NWORDS;
    for (int w = 0; w < NWORDS; ++w) {
        unsigned bits = row[w];
        while (bits) {
            int b = __ffs(bits) - 1;
            bits &= bits - 1;
            int c = w * 32 + b;
            ccol[p] = c;
            cval[p] = dr * dinv[c];
            ++p;
        }
    }
}

// thread per row: W1[r][c-c0] = S[r,c] for c in [c0, c0+B)   (W1 pre-zeroed)
__global__ void init_w1(const int* __restrict__ rowptr, const int* __restrict__ ccol,
                        const float* __restrict__ cval, float* __restrict__ W1,
                        int c0, int B) {
    int r = blockIdx.x * blockDim.x + threadIdx.x;
    if (r >= NN) return;
    int s = rowptr[r], e = rowptr[r + 1];
    float* wr = W1 + (size_t)r * B;
    for (int t = s; t < e; ++t) {
        unsigned j = (unsigned)(ccol[t] - c0);
        if (j < (unsigned)B) wr[j] = cval[t];
    }
}

// block per output row, thread per float4 column group: Wout[r,:] = sum_c S[r,c] * Win[c,:]
__global__ void spmm(const int* __restrict__ rowptr, const int* __restrict__ ccol,
                     const float* __restrict__ cval, const float* __restrict__ Win,
                     float* __restrict__ Wout, int B) {
    int r = blockIdx.x;
    int j = threadIdx.x;
    int s = rowptr[r], e = rowptr[r + 1];
    f4 acc = {0.f, 0.f, 0.f, 0.f};
    for (int t = s; t < e; ++t) {
        int c = ccol[t];
        float v = cval[t];
        const f4* src = (const f4*)(Win + (size_t)c * B);
        acc += v * src[j];
    }
    ((f4*)(Wout + (size_t)r * B))[j] = acc;
}

// column-wise reductions: nrm = sum_r Wn[r,j]^2 -> out[., tnorm]; dot = sum_r Wm*Wn -> out[., tdot]
__global__ void reduce_dotnorm(const float* __restrict__ Wm, const float* __restrict__ Wn,
                               float* __restrict__ out, int c0, int B, int tdot, int tnorm) {
    int j = blockIdx.x * blockDim.x + threadIdx.x;     // column within block
    int r0 = blockIdx.y * 512;
    const float* pn = Wn + (size_t)r0 * B + j;
    if (Wm) {
        const float* pm = Wm + (size_t)r0 * B + j;
        float nrm = 0.f, dot = 0.f;
#pragma unroll 8
        for (int r = 0; r < 512; ++r) {
            float b = pn[(size_t)r * B];
            float a = pm[(size_t)r * B];
            nrm += b * b;
            dot += a * b;
        }
        atomicAdd(out + (size_t)(c0 + j) * EMB + tdot, dot);
        atomicAdd(out + (size_t)(c0 + j) * EMB + tnorm, nrm);
    } else {
        float nrm = 0.f;
#pragma unroll 8
        for (int r = 0; r < 512; ++r) {
            float b = pn[(size_t)r * B];
            nrm += b * b;
        }
        atomicAdd(out + (size_t)(c0 + j) * EMB + tnorm, nrm);
    }
}

extern "C" void kernel_launch(void* const* d_in, const int* in_sizes, int n_in,
                              void* d_out, int out_size, void* d_ws, size_t ws_size,
                              hipStream_t stream) {
    const int* ei = (const int*)d_in[1];     // edge_index [2, nE] (int32 per harness)
    int nE = in_sizes[1] / 2;                // 131072
    float* out = (float*)d_out;

    char* ws = (char*)d_ws;
    size_t off = 0;
    auto alloc = [&](size_t bytes) -> void* {
        void* p = ws + off;
        off = (off + bytes + 255) & ~(size_t)255;
        return p;
    };
    unsigned* bm  = (unsigned*)alloc((size_t)NN * NWORDS * 4);   // 8 MB bitmap
    int*      deg = (int*)alloc((size_t)NN * 4);
    float*   dinv = (float*)alloc((size_t)NN * 4);
    int*   rowptr = (int*)alloc((size_t)(NN + 1) * 4);
    size_t maxnnz = 2 * (size_t)nE;
    int*     ccol = (int*)alloc(maxnnz * 4);
    float*   cval = (float*)alloc(maxnnz * 4);
    size_t fixed = off;

    // pick column-block width B so 2 ping-pong buffers fit the workspace;
    // 2048 keeps the 128 MB W pair L3-resident.
    int B = 2048;
    while (B > 256 && fixed + 2 * (size_t)NN * B * 4 > ws_size) B >>= 1;
    float* Wa = (float*)alloc((size_t)NN * B * 4);
    float* Wb = (float*)alloc((size_t)NN * B * 4);

    (void)hipMemsetAsync(d_out, 0, (size_t)out_size * 4, stream);
    (void)hipMemsetAsync(bm, 0, (size_t)NN * NWORDS * 4, stream);

    scatter_edges<<<(nE + 255) / 256, 256, 0, stream>>>(ei, bm, nE);
    degree_kernel<<<NN / 4, 256, 0, stream>>>(bm, deg, dinv, out);
    scan_kernel<<<1, 256, 0, stream>>>(deg, rowptr);
    fill_csr<<<NN / 256, 256, 0, stream>>>(bm, rowptr, dinv, ccol, cval);

    for (int c0 = 0; c0 < NN; c0 += B) {
        (void)hipMemsetAsync(Wa, 0, (size_t)NN * B * 4, stream);
        init_w1<<<NN / 256, 256, 0, stream>>>(rowptr, ccol, cval, Wa, c0, B);
        // k=2 (t=1): ||W1||^2
        reduce_dotnorm<<<dim3(B / 256, NN / 512), 256, 0, stream>>>(
            nullptr, Wa, out, c0, B, 0, 1);
        float* cur = Wa;
        float* nxt = Wb;
        for (int m = 1; m <= 4; ++m) {
            spmm<<<NN, B / 4, 0, stream>>>(rowptr, ccol, cval, cur, nxt, B);
            // k=2m+1 (t=2m): <W_m, W_{m+1}>;  k=2m+2 (t=2m+1): ||W_{m+1}||^2
            reduce_dotnorm<<<dim3(B / 256, NN / 512), 256, 0, stream>>>(
                cur, nxt, out, c0, B, 2 * m, 2 * m + 1);
            float* t = cur; cur = nxt; nxt = t;
        }
    }
}

// Round 2
// 3041.775 us; speedup vs baseline: 1.7771x; 1.7771x over previous
//
#include <hip/hip_runtime.h>

// RandomWalkPositionalEncoding: out[i, k-1] = diag(P^k)[i], k=1..10, P = A/(deg+1e-8)
// S = D^-1/2 A D^-1/2 (symmetric): diag(P^k) = diag(S^k);
//   diag(S^{2m}) = rowwise ||W_m||^2, diag(S^{2m+1}) = <W_m, W_{m+1}>, W_m = S^m E_block.
// W panels stored in fp16 to halve gather bytes (memory-bound per R1 rocprof).

#define NN 8192
#define NWORDS 256            // NN/32 u32 words per bitmap row
#define EMB 32

typedef _Float16 half8 __attribute__((ext_vector_type(8)));
typedef _Float16 half2t __attribute__((ext_vector_type(2)));

__global__ void scatter_edges(const int* __restrict__ ei, unsigned* __restrict__ bm, int nE) {
    int e = blockIdx.x * blockDim.x + threadIdx.x;
    if (e >= nE) return;
    int r = ei[e];
    int c = ei[nE + e];
    atomicOr(&bm[(size_t)r * NWORDS + (c >> 5)], 1u << (c & 31));
    atomicOr(&bm[(size_t)c * NWORDS + (r >> 5)], 1u << (r & 31));
}

// one wave per row: popcount 256 words, write degree, dinv_sqrt, and k=1 diagonal.
__global__ void degree_kernel(const unsigned* __restrict__ bm, int* __restrict__ deg,
                              float* __restrict__ dinv, float* __restrict__ out) {
    int lane = threadIdx.x & 63;
    int r = blockIdx.x * (blockDim.x >> 6) + (threadIdx.x >> 6);
    const unsigned* row = bm + (size_t)r * NWORDS;
    uint4 w = *(const uint4*)(row + lane * 4);
    int cnt = __popc(w.x) + __popc(w.y) + __popc(w.z) + __popc(w.w);
    for (int d = 32; d; d >>= 1) cnt += __shfl_down(cnt, d);
    if (lane == 0) {
        deg[r] = cnt;
        float dt = (float)cnt + 1e-8f;       // matches reference f32 rounding
        dinv[r] = rsqrtf(dt);
        unsigned selfw = row[r >> 5];
        out[(size_t)r * EMB] = ((selfw >> (r & 31)) & 1u) ? (1.0f / dt) : 0.0f;
    }
}

// single-block exclusive scan of 8192 degrees -> rowptr[0..8192]
__global__ void scan_kernel(const int* __restrict__ deg, int* __restrict__ rowptr) {
    __shared__ int wsum[4];
    __shared__ int base;
    int tid = threadIdx.x;          // 256 threads
    int lane = tid & 63, wid = tid >> 6;
    if (tid == 0) base = 0;
    __syncthreads();
    for (int ch = 0; ch < NN / 256; ++ch) {
        int idx = ch * 256 + tid;
        int v = deg[idx];
        int s = v;
#pragma unroll
        for (int d = 1; d < 64; d <<= 1) {
            int t = __shfl_up(s, d);
            if (lane >= d) s += t;
        }
        if (lane == 63) wsum[wid] = s;
        __syncthreads();
        int ofs = base;
        for (int w = 0; w < wid; ++w) ofs += wsum[w];
        rowptr[idx] = ofs + s - v;
        int tot = wsum[0] + wsum[1] + wsum[2] + wsum[3];
        __syncthreads();
        if (tid == 0) base += tot;
        __syncthreads();
    }
    if (tid == 0) rowptr[NN] = base;
}

// thread per row: expand bitmap row -> CSR cols + values S[r,c] = dinv[r]*dinv[c]
__global__ void fill_csr(const unsigned* __restrict__ bm, const int* __restrict__ rowptr,
                         const float* __restrict__ dinv, int* __restrict__ ccol,
                         float* __restrict__ cval) {
    int r = blockIdx.x * blockDim.x + threadIdx.x;
    if (r >= NN) return;
    int p = rowptr[r];
    float dr = dinv[r];
    const unsigned* row = bm + (size_t)r * NWORDS;
    for (int w = 0; w < NWORDS; ++w) {
        unsigned bits = row[w];
        while (bits) {
            int b = __ffs(bits) - 1;
            bits &= bits - 1;
            int c = w * 32 + b;
            ccol[p] = c;
            cval[p] = dr * dinv[c];
            ++p;
        }
    }
}

// thread per row: W1[r][c-c0] = S[r,c] for c in [c0, c0+B)   (W1 pre-zeroed)
__global__ void init_w1(const int* __restrict__ rowptr, const int* __restrict__ ccol,
                        const float* __restrict__ cval, _Float16* __restrict__ W1,
                        int c0, int B) {
    int r = blockIdx.x * blockDim.x + threadIdx.x;
    if (r >= NN) return;
    int s = rowptr[r], e = rowptr[r + 1];
    _Float16* wr = W1 + (size_t)r * B;
    for (int t = s; t < e; ++t) {
        unsigned j = (unsigned)(ccol[t] - c0);
        if (j < (unsigned)B) wr[j] = (_Float16)cval[t];
    }
}

// block per output row, thread per 8-wide fp16 column group:
// Wout[r,:] = sum_c S[r,c] * Win[c,:]
__global__ void spmm(const int* __restrict__ rowptr, const int* __restrict__ ccol,
                     const float* __restrict__ cval, const _Float16* __restrict__ Win,
                     _Float16* __restrict__ Wout, int B) {
    int r = blockIdx.x;
    int j = threadIdx.x;
    int s = rowptr[r], e = rowptr[r + 1];
    float acc[8] = {0.f, 0.f, 0.f, 0.f, 0.f, 0.f, 0.f, 0.f};
    int t = s;
    for (; t + 2 <= e; t += 2) {
        int c0 = ccol[t], c1 = ccol[t + 1];
        float v0 = cval[t], v1 = cval[t + 1];
        half8 s0 = ((const half8*)(Win + (size_t)c0 * B))[j];
        half8 s1 = ((const half8*)(Win + (size_t)c1 * B))[j];
#pragma unroll
        for (int k = 0; k < 8; ++k) acc[k] += v0 * (float)s0[k] + v1 * (float)s1[k];
    }
    if (t < e) {
        int c0 = ccol[t];
        float v0 = cval[t];
        half8 s0 = ((const half8*)(Win + (size_t)c0 * B))[j];
#pragma unroll
        for (int k = 0; k < 8; ++k) acc[k] += v0 * (float)s0[k];
    }
    half8 o;
#pragma unroll
    for (int k = 0; k < 8; ++k) o[k] = (_Float16)acc[k];
    ((half8*)(Wout + (size_t)r * B))[j] = o;
}

// column-wise reductions over rows: nrm_j = sum_r Wn[r,j]^2 -> out[., tnorm];
// dot_j = sum_r Wm[r,j]*Wn[r,j] -> out[., tdot].  Each thread owns 2 adjacent columns.
__global__ void reduce_dotnorm(const _Float16* __restrict__ Wm, const _Float16* __restrict__ Wn,
                               float* __restrict__ out, int c0, int B, int tdot, int tnorm) {
    int j = (blockIdx.x * blockDim.x + threadIdx.x) * 2;   // column pair within block
    int r0 = blockIdx.y * 512;
    const _Float16* pn = Wn + (size_t)r0 * B + j;
    if (Wm) {
        const _Float16* pm = Wm + (size_t)r0 * B + j;
        float n0 = 0.f, n1 = 0.f, d0 = 0.f, d1 = 0.f;
#pragma unroll 4
        for (int r = 0; r < 512; ++r) {
            half2t b = *(const half2t*)(pn + (size_t)r * B);
            half2t a = *(const half2t*)(pm + (size_t)r * B);
            float b0 = (float)b[0], b1 = (float)b[1];
            n0 += b0 * b0; n1 += b1 * b1;
            d0 += (float)a[0] * b0; d1 += (float)a[1] * b1;
        }
        atomicAdd(out + (size_t)(c0 + j) * EMB + tdot, d0);
        atomicAdd(out + (size_t)(c0 + j) * EMB + tnorm, n0);
        atomicAdd(out + (size_t)(c0 + j + 1) * EMB + tdot, d1);
        atomicAdd(out + (size_t)(c0 + j + 1) * EMB + tnorm, n1);
    } else {
        float n0 = 0.f, n1 = 0.f;
#pragma unroll 4
        for (int r = 0; r < 512; ++r) {
            half2t b = *(const half2t*)(pn + (size_t)r * B);
            n0 += (float)b[0] * (float)b[0];
            n1 += (float)b[1] * (float)b[1];
        }
        atomicAdd(out + (size_t)(c0 + j) * EMB + tnorm, n0);
        atomicAdd(out + (size_t)(c0 + j + 1) * EMB + tnorm, n1);
    }
}

extern "C" void kernel_launch(void* const* d_in, const int* in_sizes, int n_in,
                              void* d_out, int out_size, void* d_ws, size_t ws_size,
                              hipStream_t stream) {
    const int* ei = (const int*)d_in[1];     // edge_index [2, nE]
    int nE = in_sizes[1] / 2;                // 131072
    float* out = (float*)d_out;

    char* ws = (char*)d_ws;
    size_t off = 0;
    auto alloc = [&](size_t bytes) -> void* {
        void* p = ws + off;
        off = (off + bytes + 255) & ~(size_t)255;
        return p;
    };
    unsigned* bm  = (unsigned*)alloc((size_t)NN * NWORDS * 4);   // 8 MB bitmap
    int*      deg = (int*)alloc((size_t)NN * 4);
    float*   dinv = (float*)alloc((size_t)NN * 4);
    int*   rowptr = (int*)alloc((size_t)(NN + 1) * 4);
    size_t maxnnz = 2 * (size_t)nE;
    int*     ccol = (int*)alloc(maxnnz * 4);
    float*   cval = (float*)alloc(maxnnz * 4);
    size_t fixed = off;

    // column-block width: fp16 panels, pair must fit workspace. 4096 -> 128 MB pair.
    int B = 4096;
    while (B > 512 && fixed + 2 * (size_t)NN * B * 2 > ws_size) B >>= 1;
    _Float16* Wa = (_Float16*)alloc((size_t)NN * B * 2);
    _Float16* Wb = (_Float16*)alloc((size_t)NN * B * 2);

    (void)hipMemsetAsync(d_out, 0, (size_t)out_size * 4, stream);
    (void)hipMemsetAsync(bm, 0, (size_t)NN * NWORDS * 4, stream);

    scatter_edges<<<(nE + 255) / 256, 256, 0, stream>>>(ei, bm, nE);
    degree_kernel<<<NN / 4, 256, 0, stream>>>(bm, deg, dinv, out);
    scan_kernel<<<1, 256, 0, stream>>>(deg, rowptr);
    fill_csr<<<NN / 256, 256, 0, stream>>>(bm, rowptr, dinv, ccol, cval);

    for (int c0 = 0; c0 < NN; c0 += B) {
        (void)hipMemsetAsync(Wa, 0, (size_t)NN * B * 2, stream);
        init_w1<<<NN / 256, 256, 0, stream>>>(rowptr, ccol, cval, Wa, c0, B);
        // k=2 (t=1): ||W1||^2
        reduce_dotnorm<<<dim3(B / 512, NN / 512), 256, 0, stream>>>(
            nullptr, Wa, out, c0, B, 0, 1);
        _Float16* cur = Wa;
        _Float16* nxt = Wb;
        for (int m = 1; m <= 4; ++m) {
            spmm<<<NN, B / 8, 0, stream>>>(rowptr, ccol, cval, cur, nxt, B);
            // k=2m+1 (t=2m): <W_m, W_{m+1}>;  k=2m+2 (t=2m+1): ||W_{m+1}||^2
            reduce_dotnorm<<<dim3(B / 512, NN / 512), 256, 0, stream>>>(
                cur, nxt, out, c0, B, 2 * m, 2 * m + 1);
            _Float16* t = cur; cur = nxt; nxt = t;
        }
    }
}

// Round 3
// 2149.515 us; speedup vs baseline: 2.5147x; 1.4151x over previous
//
#include <hip/hip_runtime.h>

// RandomWalkPositionalEncoding: out[i, k-1] = diag(P^k)[i], k=1..10, P = A/(deg+1e-8)
// S = D^-1/2 A D^-1/2 (symmetric): diag(P^k) = diag(S^k);
//   diag(S^{2m}) = rowwise ||W_m||^2, diag(S^{2m+1}) = <W_m, W_{m+1}>, W_m = S^m E_block.
// fp16 panels; SpMM gathers made L2-resident via XCD column-partitioning (blockIdx&7)
// + source-row tiling (8 tiles x 1024 rows, per-row segment offsets in rowptr2).

#define NN 8192
#define NWORDS 256            // NN/32 u32 words per bitmap row
#define EMB 32
#define TROWS 1024            // source-row tile height
#define NT 8                  // NN / TROWS

typedef _Float16 half8 __attribute__((ext_vector_type(8)));
typedef _Float16 half2t __attribute__((ext_vector_type(2)));

__global__ void scatter_edges(const int* __restrict__ ei, unsigned* __restrict__ bm, int nE) {
    int e = blockIdx.x * blockDim.x + threadIdx.x;
    if (e >= nE) return;
    int r = ei[e];
    int c = ei[nE + e];
    atomicOr(&bm[(size_t)r * NWORDS + (c >> 5)], 1u << (c & 31));
    atomicOr(&bm[(size_t)c * NWORDS + (r >> 5)], 1u << (r & 31));
}

// one wave per row: popcount 256 words, write degree, dinv_sqrt, and k=1 diagonal.
__global__ void degree_kernel(const unsigned* __restrict__ bm, int* __restrict__ deg,
                              float* __restrict__ dinv, float* __restrict__ out) {
    int lane = threadIdx.x & 63;
    int r = blockIdx.x * (blockDim.x >> 6) + (threadIdx.x >> 6);
    const unsigned* row = bm + (size_t)r * NWORDS;
    uint4 w = *(const uint4*)(row + lane * 4);
    int cnt = __popc(w.x) + __popc(w.y) + __popc(w.z) + __popc(w.w);
    for (int d = 32; d; d >>= 1) cnt += __shfl_down(cnt, d);
    if (lane == 0) {
        deg[r] = cnt;
        float dt = (float)cnt + 1e-8f;       // matches reference f32 rounding
        dinv[r] = rsqrtf(dt);
        unsigned selfw = row[r >> 5];
        out[(size_t)r * EMB] = ((selfw >> (r & 31)) & 1u) ? (1.0f / dt) : 0.0f;
    }
}

// single-block exclusive scan of 8192 degrees -> rowptr[0..8192]
__global__ void scan_kernel(const int* __restrict__ deg, int* __restrict__ rowptr) {
    __shared__ int wsum[4];
    __shared__ int base;
    int tid = threadIdx.x;          // 256 threads
    int lane = tid & 63, wid = tid >> 6;
    if (tid == 0) base = 0;
    __syncthreads();
    for (int ch = 0; ch < NN / 256; ++ch) {
        int idx = ch * 256 + tid;
        int v = deg[idx];
        int s = v;
#pragma unroll
        for (int d = 1; d < 64; d <<= 1) {
            int t = __shfl_up(s, d);
            if (lane >= d) s += t;
        }
        if (lane == 63) wsum[wid] = s;
        __syncthreads();
        int ofs = base;
        for (int w = 0; w < wid; ++w) ofs += wsum[w];
        rowptr[idx] = ofs + s - v;
        int tot = wsum[0] + wsum[1] + wsum[2] + wsum[3];
        __syncthreads();
        if (tid == 0) base += tot;
        __syncthreads();
    }
    if (tid == 0) rowptr[NN] = base;
}

// thread per row: expand bitmap row -> u16 CSR cols (values recomputed on the fly later)
__global__ void fill_csr(const unsigned* __restrict__ bm, const int* __restrict__ rowptr,
                         unsigned short* __restrict__ ccol) {
    int r = blockIdx.x * blockDim.x + threadIdx.x;
    if (r >= NN) return;
    int p = rowptr[r];
    const unsigned* row = bm + (size_t)r * NWORDS;
    for (int w = 0; w < NWORDS; ++w) {
        unsigned bits = row[w];
        while (bits) {
            int b = __ffs(bits) - 1;
            bits &= bits - 1;
            ccol[p++] = (unsigned short)(w * 32 + b);
        }
    }
}

// thread per row: per-tile segment offsets (cols are sorted within a row)
__global__ void seg_kernel(const int* __restrict__ rowptr, const unsigned short* __restrict__ ccol,
                           int* __restrict__ rowptr2) {
    int r = blockIdx.x * blockDim.x + threadIdx.x;
    if (r >= NN) return;
    int e = rowptr[r + 1];
    int p = rowptr[r];
    int* rp2 = rowptr2 + (size_t)r * (NT + 1);
    for (int t = 0; t < NT; ++t) {
        rp2[t] = p;
        int lim = (t + 1) * TROWS;
        while (p < e && ccol[p] < lim) ++p;
    }
    rp2[NT] = e;
}

// thread per row: W1[r][c-c0] = S[r,c] for c in [c0, c0+B)   (W1 pre-zeroed)
__global__ void init_w1(const int* __restrict__ rowptr, const unsigned short* __restrict__ ccol,
                        const float* __restrict__ dinv, _Float16* __restrict__ W1,
                        int c0, int B) {
    int r = blockIdx.x * blockDim.x + threadIdx.x;
    if (r >= NN) return;
    int s = rowptr[r], e = rowptr[r + 1];
    float dr = dinv[r];
    _Float16* wr = W1 + (size_t)r * B;
    for (int t = s; t < e; ++t) {
        int c = ccol[t];
        unsigned j = (unsigned)(c - c0);
        if (j < (unsigned)B) wr[j] = (_Float16)(dr * dinv[c]);
    }
}

// Wout[r, cols of group g] = sum_c S[r,c] * Win[c, cols of group g]
// col-group g = blockIdx&7 pins the group's 1/8 column slice to one XCD's L2;
// source-tile loop keeps the gather target slice (TROWS x GCOLS fp16 = 1 MB) resident.
__global__ void spmm_tiled(const int* __restrict__ rowptr2, const unsigned short* __restrict__ ccol,
                           const float* __restrict__ dinv, const _Float16* __restrict__ Win,
                           _Float16* __restrict__ Wout, int B) {
    int gcols = B >> 3;                    // columns per group
    int tpr = gcols >> 3;                  // threads per row (8 cols each)
    int rpb = 256 / tpr;                   // rows per block
    int g = blockIdx.x & 7;
    int rblk = blockIdx.x >> 3;
    int r = rblk * rpb + (int)(threadIdx.x / tpr);
    int lane = (int)(threadIdx.x % tpr);
    int j = g * gcols + lane * 8;
    float dr = dinv[r];
    float acc[8] = {0.f, 0.f, 0.f, 0.f, 0.f, 0.f, 0.f, 0.f};
    const int* rp2 = rowptr2 + (size_t)r * (NT + 1);
    int p = rp2[0];
#pragma unroll 1
    for (int t = 0; t < NT; ++t) {
        int e = rp2[t + 1];
        for (; p + 2 <= e; p += 2) {
            int c0 = ccol[p], c1 = ccol[p + 1];
            float v0 = dr * dinv[c0], v1 = dr * dinv[c1];
            half8 s0 = *(const half8*)(Win + (size_t)c0 * B + j);
            half8 s1 = *(const half8*)(Win + (size_t)c1 * B + j);
#pragma unroll
            for (int k = 0; k < 8; ++k) acc[k] += v0 * (float)s0[k] + v1 * (float)s1[k];
        }
        if (p < e) {
            int c0 = ccol[p++];
            float v0 = dr * dinv[c0];
            half8 s0 = *(const half8*)(Win + (size_t)c0 * B + j);
#pragma unroll
            for (int k = 0; k < 8; ++k) acc[k] += v0 * (float)s0[k];
        }
    }
    half8 o;
#pragma unroll
    for (int k = 0; k < 8; ++k) o[k] = (_Float16)acc[k];
    *(half8*)(Wout + (size_t)r * B + j) = o;
}

// column-wise reductions over rows, col-group aware (blockIdx.x&7 matches spmm's XCD):
// nrm_j = sum_r Wn[r,j]^2 -> out[., tnorm]; dot_j = sum_r Wm[r,j]*Wn[r,j] -> out[., tdot].
__global__ void reduce_dotnorm(const _Float16* __restrict__ Wm, const _Float16* __restrict__ Wn,
                               float* __restrict__ out, int c0, int B, int tdot, int tnorm) {
    int gcols = B >> 3;
    int g = blockIdx.x & 7;
    int cpt = gcols / 256;                              // cols per thread (>=2)
    int j = g * gcols + threadIdx.x * cpt;
    int r0 = blockIdx.y * 512;
    for (int jj = j; jj < j + cpt; jj += 2) {
        const _Float16* pn = Wn + (size_t)r0 * B + jj;
        if (Wm) {
            const _Float16* pm = Wm + (size_t)r0 * B + jj;
            float n0 = 0.f, n1 = 0.f, d0 = 0.f, d1 = 0.f;
#pragma unroll 4
            for (int r = 0; r < 512; ++r) {
                half2t b = *(const half2t*)(pn + (size_t)r * B);
                half2t a = *(const half2t*)(pm + (size_t)r * B);
                float b0 = (float)b[0], b1 = (float)b[1];
                n0 += b0 * b0; n1 += b1 * b1;
                d0 += (float)a[0] * b0; d1 += (float)a[1] * b1;
            }
            atomicAdd(out + (size_t)(c0 + jj) * EMB + tdot, d0);
            atomicAdd(out + (size_t)(c0 + jj) * EMB + tnorm, n0);
            atomicAdd(out + (size_t)(c0 + jj + 1) * EMB + tdot, d1);
            atomicAdd(out + (size_t)(c0 + jj + 1) * EMB + tnorm, n1);
        } else {
            float n0 = 0.f, n1 = 0.f;
#pragma unroll 4
            for (int r = 0; r < 512; ++r) {
                half2t b = *(const half2t*)(pn + (size_t)r * B);
                n0 += (float)b[0] * (float)b[0];
                n1 += (float)b[1] * (float)b[1];
            }
            atomicAdd(out + (size_t)(c0 + jj) * EMB + tnorm, n0);
            atomicAdd(out + (size_t)(c0 + jj + 1) * EMB + tnorm, n1);
        }
    }
}

extern "C" void kernel_launch(void* const* d_in, const int* in_sizes, int n_in,
                              void* d_out, int out_size, void* d_ws, size_t ws_size,
                              hipStream_t stream) {
    const int* ei = (const int*)d_in[1];     // edge_index [2, nE]
    int nE = in_sizes[1] / 2;                // 131072
    float* out = (float*)d_out;

    char* ws = (char*)d_ws;
    size_t off = 0;
    auto alloc = [&](size_t bytes) -> void* {
        void* p = ws + off;
        off = (off + bytes + 255) & ~(size_t)255;
        return p;
    };
    unsigned* bm  = (unsigned*)alloc((size_t)NN * NWORDS * 4);   // 8 MB bitmap
    int*      deg = (int*)alloc((size_t)NN * 4);
    float*   dinv = (float*)alloc((size_t)NN * 4);
    int*   rowptr = (int*)alloc((size_t)(NN + 1) * 4);
    size_t maxnnz = 2 * (size_t)nE;
    unsigned short* ccol = (unsigned short*)alloc(maxnnz * 2);
    int*  rowptr2 = (int*)alloc((size_t)NN * (NT + 1) * 4);
    size_t fixed = off;

    // column-block width: fp16 panel pair must fit workspace. 4096 -> 128 MB pair.
    int B = 4096;
    while (B > 512 && fixed + 2 * (size_t)NN * B * 2 > ws_size) B >>= 1;
    _Float16* Wa = (_Float16*)alloc((size_t)NN * B * 2);
    _Float16* Wb = (_Float16*)alloc((size_t)NN * B * 2);

    (void)hipMemsetAsync(d_out, 0, (size_t)out_size * 4, stream);
    (void)hipMemsetAsync(bm, 0, (size_t)NN * NWORDS * 4, stream);

    scatter_edges<<<(nE + 255) / 256, 256, 0, stream>>>(ei, bm, nE);
    degree_kernel<<<NN / 4, 256, 0, stream>>>(bm, deg, dinv, out);
    scan_kernel<<<1, 256, 0, stream>>>(deg, rowptr);
    fill_csr<<<NN / 256, 256, 0, stream>>>(bm, rowptr, ccol);
    seg_kernel<<<NN / 256, 256, 0, stream>>>(rowptr, ccol, rowptr2);

    int gcols = B >> 3;
    int tpr = gcols >> 3;
    int rpb = 256 / tpr;
    dim3 spmm_grid(8 * (NN / rpb));
    dim3 red_grid(8, NN / 512);

    for (int c0 = 0; c0 < NN; c0 += B) {
        (void)hipMemsetAsync(Wa, 0, (size_t)NN * B * 2, stream);
        init_w1<<<NN / 256, 256, 0, stream>>>(rowptr, ccol, dinv, Wa, c0, B);
        // k=2 (t=1): ||W1||^2
        reduce_dotnorm<<<red_grid, 256, 0, stream>>>(nullptr, Wa, out, c0, B, 0, 1);
        _Float16* cur = Wa;
        _Float16* nxt = Wb;
        for (int m = 1; m <= 4; ++m) {
            spmm_tiled<<<spmm_grid, 256, 0, stream>>>(rowptr2, ccol, dinv, cur, nxt, B);
            // k=2m+1 (t=2m): <W_m, W_{m+1}>;  k=2m+2 (t=2m+1): ||W_{m+1}||^2
            reduce_dotnorm<<<red_grid, 256, 0, stream>>>(cur, nxt, out, c0, B, 2 * m, 2 * m + 1);
            _Float16* t = cur; cur = nxt; nxt = t;
        }
    }
}

// Round 4
// 1713.370 us; speedup vs baseline: 3.1549x; 1.2546x over previous
//
#include <hip/hip_runtime.h>

// RandomWalkPositionalEncoding: out[i, k-1] = diag(P^k)[i], k=1..10, P = A/(deg+1e-8)
// S = D^-1/2 A D^-1/2 (symmetric): diag(P^k) = diag(S^k);
//   diag(S^2)[j] analytic = dinv_j^2 * sum_{c in N(j)} dinv_c^2,
//   diag(S^{2m}) = rowwise ||W_m||^2, diag(S^{2m+1}) = <W_m, W_{m+1}>, W_m = S^m E_block.
// fp16 panels. SpMM: 128-col groups (2 MB slice, L2-resident per XCD via blockIdx&7
// round-robin + sub-group-major launch order); non-temporal output stores.

#define NN 8192
#define NWORDS 256            // NN/32 u32 words per bitmap row
#define EMB 32
#define GCOLS 128             // columns per group (slice = NN*GCOLS*2 = 2 MB)
#define TPR 16                // threads per row (16 x 8 cols = 128)
#define RPB 16                // rows per block (256 threads)

typedef _Float16 half8 __attribute__((ext_vector_type(8)));
typedef _Float16 half2t __attribute__((ext_vector_type(2)));
typedef unsigned int u32x4 __attribute__((ext_vector_type(4)));

__global__ void scatter_edges(const int* __restrict__ ei, unsigned* __restrict__ bm, int nE) {
    int e = blockIdx.x * blockDim.x + threadIdx.x;
    if (e >= nE) return;
    int r = ei[e];
    int c = ei[nE + e];
    atomicOr(&bm[(size_t)r * NWORDS + (c >> 5)], 1u << (c & 31));
    atomicOr(&bm[(size_t)c * NWORDS + (r >> 5)], 1u << (r & 31));
}

// one wave per row: popcount 256 words, write degree, dinv_sqrt, and k=1 diagonal.
__global__ void degree_kernel(const unsigned* __restrict__ bm, int* __restrict__ deg,
                              float* __restrict__ dinv, float* __restrict__ out) {
    int lane = threadIdx.x & 63;
    int r = blockIdx.x * (blockDim.x >> 6) + (threadIdx.x >> 6);
    const unsigned* row = bm + (size_t)r * NWORDS;
    uint4 w = *(const uint4*)(row + lane * 4);
    int cnt = __popc(w.x) + __popc(w.y) + __popc(w.z) + __popc(w.w);
    for (int d = 32; d; d >>= 1) cnt += __shfl_down(cnt, d);
    if (lane == 0) {
        deg[r] = cnt;
        float dt = (float)cnt + 1e-8f;       // matches reference f32 rounding
        dinv[r] = rsqrtf(dt);
        unsigned selfw = row[r >> 5];
        out[(size_t)r * EMB] = ((selfw >> (r & 31)) & 1u) ? (1.0f / dt) : 0.0f;
    }
}

// single-block exclusive scan of 8192 degrees -> rowptr[0..8192]
__global__ void scan_kernel(const int* __restrict__ deg, int* __restrict__ rowptr) {
    __shared__ int wsum[4];
    __shared__ int base;
    int tid = threadIdx.x;          // 256 threads
    int lane = tid & 63, wid = tid >> 6;
    if (tid == 0) base = 0;
    __syncthreads();
    for (int ch = 0; ch < NN / 256; ++ch) {
        int idx = ch * 256 + tid;
        int v = deg[idx];
        int s = v;
#pragma unroll
        for (int d = 1; d < 64; d <<= 1) {
            int t = __shfl_up(s, d);
            if (lane >= d) s += t;
        }
        if (lane == 63) wsum[wid] = s;
        __syncthreads();
        int ofs = base;
        for (int w = 0; w < wid; ++w) ofs += wsum[w];
        rowptr[idx] = ofs + s - v;
        int tot = wsum[0] + wsum[1] + wsum[2] + wsum[3];
        __syncthreads();
        if (tid == 0) base += tot;
        __syncthreads();
    }
    if (tid == 0) rowptr[NN] = base;
}

// thread per row: expand bitmap row -> u16 CSR cols (values recomputed on the fly later)
__global__ void fill_csr(const unsigned* __restrict__ bm, const int* __restrict__ rowptr,
                         unsigned short* __restrict__ ccol) {
    int r = blockIdx.x * blockDim.x + threadIdx.x;
    if (r >= NN) return;
    int p = rowptr[r];
    const unsigned* row = bm + (size_t)r * NWORDS;
    for (int w = 0; w < NWORDS; ++w) {
        unsigned bits = row[w];
        while (bits) {
            int b = __ffs(bits) - 1;
            bits &= bits - 1;
            ccol[p++] = (unsigned short)(w * 32 + b);
        }
    }
}

// diag(S^2)[r] = dinv_r^2 * sum_{c in N(r)} dinv_c^2   (exact, f32 — replaces norm reduce)
__global__ void diag2_kernel(const int* __restrict__ rowptr, const unsigned short* __restrict__ ccol,
                             const float* __restrict__ dinv, float* __restrict__ out) {
    int r = blockIdx.x * blockDim.x + threadIdx.x;
    if (r >= NN) return;
    int s = rowptr[r], e = rowptr[r + 1];
    float acc = 0.f;
    for (int p = s; p < e; ++p) {
        float d = dinv[ccol[p]];
        acc += d * d;
    }
    float dr = dinv[r];
    out[(size_t)r * EMB + 1] = dr * dr * acc;
}

// thread per row: W1[r][c-c0] = S[r,c] for c in [c0, c0+B)   (W1 pre-zeroed)
__global__ void init_w1(const int* __restrict__ rowptr, const unsigned short* __restrict__ ccol,
                        const float* __restrict__ dinv, _Float16* __restrict__ W1,
                        int c0, int B) {
    int r = blockIdx.x * blockDim.x + threadIdx.x;
    if (r >= NN) return;
    int s = rowptr[r], e = rowptr[r + 1];
    float dr = dinv[r];
    _Float16* wr = W1 + (size_t)r * B;
    for (int t = s; t < e; ++t) {
        int c = ccol[t];
        unsigned j = (unsigned)(c - c0);
        if (j < (unsigned)B) wr[j] = (_Float16)(dr * dinv[c]);
    }
}

// Wout[r, cols of group grp] = sum_c S[r,c] * Win[c, cols of group grp]
// grp's 128-col slice (2 MB) stays L2-resident on its XCD: xcd = blockIdx&7 maps to the
// round-robin XCD assignment; higher bits enumerate sub-groups major so the resident
// block window per XCD covers <=2 slices. Non-temporal store keeps writes out of L2.
__global__ void spmm_grp(const int* __restrict__ rowptr, const unsigned short* __restrict__ ccol,
                         const float* __restrict__ dinv, const _Float16* __restrict__ Win,
                         _Float16* __restrict__ Wout, int B, int SUBS) {
    const int rpg = NN / RPB;                 // row-blocks per group = 512
    int i = blockIdx.x;
    int xcd = i & 7;
    int q = i >> 3;
    int sub = q / rpg;
    int rblk = q - sub * rpg;
    int grp = xcd * SUBS + sub;
    int lane = threadIdx.x & (TPR - 1);
    int r = rblk * RPB + (threadIdx.x >> 4);
    int j = grp * GCOLS + lane * 8;
    float dr = dinv[r];
    int p = rowptr[r], e = rowptr[r + 1];
    const _Float16* base = Win + j;
    float acc[8] = {0.f, 0.f, 0.f, 0.f, 0.f, 0.f, 0.f, 0.f};
    for (; p + 2 <= e; p += 2) {
        int c0 = ccol[p], c1 = ccol[p + 1];
        float v0 = dr * dinv[c0], v1 = dr * dinv[c1];
        half8 s0 = *(const half8*)(base + (size_t)c0 * B);
        half8 s1 = *(const half8*)(base + (size_t)c1 * B);
#pragma unroll
        for (int k = 0; k < 8; ++k) acc[k] += v0 * (float)s0[k] + v1 * (float)s1[k];
    }
    if (p < e) {
        int c0 = ccol[p];
        float v0 = dr * dinv[c0];
        half8 s0 = *(const half8*)(base + (size_t)c0 * B);
#pragma unroll
        for (int k = 0; k < 8; ++k) acc[k] += v0 * (float)s0[k];
    }
    union { half8 h; u32x4 u; } o;
#pragma unroll
    for (int k = 0; k < 8; ++k) o.h[k] = (_Float16)acc[k];
    __builtin_nontemporal_store(o.u, (u32x4*)(Wout + (size_t)r * B + j));
}

// column-wise reductions over rows: dot_j = sum_r Wm[r,j]*Wn[r,j] -> out[., tdot];
// nrm_j = sum_r Wn[r,j]^2 -> out[., tnorm].  Thread: 2 cols x 128 rows.
__global__ void reduce_dotnorm(const _Float16* __restrict__ Wm, const _Float16* __restrict__ Wn,
                               float* __restrict__ out, int c0, int B, int tdot, int tnorm) {
    int j = (blockIdx.x * blockDim.x + threadIdx.x) * 2;
    int r0 = blockIdx.y * 128;
    const _Float16* pn = Wn + (size_t)r0 * B + j;
    const _Float16* pm = Wm + (size_t)r0 * B + j;
    float n0 = 0.f, n1 = 0.f, d0 = 0.f, d1 = 0.f;
#pragma unroll 4
    for (int r = 0; r < 128; ++r) {
        half2t b = *(const half2t*)(pn + (size_t)r * B);
        half2t a = *(const half2t*)(pm + (size_t)r * B);
        float b0 = (float)b[0], b1 = (float)b[1];
        n0 += b0 * b0; n1 += b1 * b1;
        d0 += (float)a[0] * b0; d1 += (float)a[1] * b1;
    }
    atomicAdd(out + (size_t)(c0 + j) * EMB + tdot, d0);
    atomicAdd(out + (size_t)(c0 + j) * EMB + tnorm, n0);
    atomicAdd(out + (size_t)(c0 + j + 1) * EMB + tdot, d1);
    atomicAdd(out + (size_t)(c0 + j + 1) * EMB + tnorm, n1);
}

extern "C" void kernel_launch(void* const* d_in, const int* in_sizes, int n_in,
                              void* d_out, int out_size, void* d_ws, size_t ws_size,
                              hipStream_t stream) {
    const int* ei = (const int*)d_in[1];     // edge_index [2, nE]
    int nE = in_sizes[1] / 2;                // 131072
    float* out = (float*)d_out;

    char* ws = (char*)d_ws;
    size_t off = 0;
    auto alloc = [&](size_t bytes) -> void* {
        void* p = ws + off;
        off = (off + bytes + 255) & ~(size_t)255;
        return p;
    };
    unsigned* bm  = (unsigned*)alloc((size_t)NN * NWORDS * 4);   // 8 MB bitmap
    int*      deg = (int*)alloc((size_t)NN * 4);
    float*   dinv = (float*)alloc((size_t)NN * 4);
    int*   rowptr = (int*)alloc((size_t)(NN + 1) * 4);
    size_t maxnnz = 2 * (size_t)nE;
    unsigned short* ccol = (unsigned short*)alloc(maxnnz * 2);
    size_t fixed = off;

    // column-block width: fp16 panel pair must fit workspace. 4096 -> 128 MB pair.
    int B = 4096;
    while (B > 1024 && fixed + 2 * (size_t)NN * B * 2 > ws_size) B >>= 1;
    _Float16* Wa = (_Float16*)alloc((size_t)NN * B * 2);
    _Float16* Wb = (_Float16*)alloc((size_t)NN * B * 2);
    int SUBS = (B / GCOLS) / 8;              // col-group slices per XCD (4 at B=4096)

    (void)hipMemsetAsync(d_out, 0, (size_t)out_size * 4, stream);
    (void)hipMemsetAsync(bm, 0, (size_t)NN * NWORDS * 4, stream);

    scatter_edges<<<(nE + 255) / 256, 256, 0, stream>>>(ei, bm, nE);
    degree_kernel<<<NN / 4, 256, 0, stream>>>(bm, deg, dinv, out);
    scan_kernel<<<1, 256, 0, stream>>>(deg, rowptr);
    fill_csr<<<NN / 256, 256, 0, stream>>>(bm, rowptr, ccol);
    diag2_kernel<<<NN / 256, 256, 0, stream>>>(rowptr, ccol, dinv, out);

    dim3 spmm_grid(8 * SUBS * (NN / RPB));
    dim3 red_grid(B / 512, NN / 128);

    for (int c0 = 0; c0 < NN; c0 += B) {
        (void)hipMemsetAsync(Wa, 0, (size_t)NN * B * 2, stream);
        init_w1<<<NN / 256, 256, 0, stream>>>(rowptr, ccol, dinv, Wa, c0, B);
        _Float16* cur = Wa;
        _Float16* nxt = Wb;
        for (int m = 1; m <= 4; ++m) {
            spmm_grp<<<spmm_grid, 256, 0, stream>>>(rowptr, ccol, dinv, cur, nxt, B, SUBS);
            // k=2m+1 (t=2m): <W_m, W_{m+1}>;  k=2m+2 (t=2m+1): ||W_{m+1}||^2
            reduce_dotnorm<<<red_grid, 256, 0, stream>>>(cur, nxt, out, c0, B, 2 * m, 2 * m + 1);
            _Float16* t = cur; cur = nxt; nxt = t;
        }
    }
}